// Round 2
// baseline (3851.603 us; speedup 1.0000x reference)
//
#include <hip/hip_runtime.h>
#include <math.h>

// ---------------------------------------------------------------------------
// CGNR solver (fp32): v = argmin ||H v - x|| via CG on (H^T H) v = H^T x,
// 32 iters, then reconstruction + time/frequency-domain metrics.
// N = 8192, H fp32 row-major. Memory-bound: 66 passes over 256 MB of H.
// ---------------------------------------------------------------------------

#define NN 8192
#define NITER 32
#define EPSF 1e-20f

__device__ __forceinline__ float wave_red(float v) {
    #pragma unroll
    for (int off = 32; off; off >>= 1) v += __shfl_xor(v, off, 64);
    return v;
}

__device__ __forceinline__ void wred_atomic(float v, float* addr) {
    v = wave_red(v);
    if ((threadIdx.x & 63) == 0) atomicAdd(addr, v);
}

// --- y = H * src  (row dot products). One wave per row. -------------------
__global__ __launch_bounds__(256) void rowdot(const float* __restrict__ H,
                                              const float* __restrict__ src,
                                              float* __restrict__ y) {
    const int wave = threadIdx.x >> 6;
    const int lane = threadIdx.x & 63;
    const int row  = blockIdx.x * 4 + wave;
    const float4* Hrow = (const float4*)(H + (size_t)row * NN);
    const float4* s4   = (const float4*)src;
    float acc = 0.f;
    #pragma unroll 4
    for (int it = 0; it < 32; ++it) {
        const int idx = it * 64 + lane;     // float4 index
        float4 h = Hrow[idx];
        float4 s = s4[idx];
        acc += h.x * s.x + h.y * s.y + h.z * s.z + h.w * s.w;
    }
    acc = wave_red(acc);
    if (lane == 0) y[row] = acc;
}

// --- y += H^T * src (column accumulate, coalesced row-wise reads). ---------
// 8 col-stripes x 64 row-blocks; block: 128 rows x 1024 cols;
// thread owns 4 consecutive columns (one float4 per row).
#define CM_ROWS 128
__global__ __launch_bounds__(256) void colmv(const float* __restrict__ H,
                                             const float* __restrict__ src,
                                             float* __restrict__ y) {
    const int stripe = blockIdx.x & 7;
    const int rb     = blockIdx.x >> 3;
    const int col    = stripe * 1024 + threadIdx.x * 4;
    const int r0     = rb * CM_ROWS;
    __shared__ float s[CM_ROWS];
    if (threadIdx.x < CM_ROWS) s[threadIdx.x] = src[r0 + threadIdx.x];
    __syncthreads();
    float a0 = 0.f, a1 = 0.f, a2 = 0.f, a3 = 0.f;
    const float* Hp = H + (size_t)r0 * NN + col;
    #pragma unroll 8
    for (int i = 0; i < CM_ROWS; ++i) {
        float4 u = *(const float4*)(Hp + (size_t)i * NN);
        const float sv = s[i];
        a0 += u.x * sv; a1 += u.y * sv; a2 += u.z * sv; a3 += u.w * sv;
    }
    atomicAdd(&y[col + 0], a0); atomicAdd(&y[col + 1], a1);
    atomicAdd(&y[col + 2], a2); atomicAdd(&y[col + 3], a3);
}

// --- prep: zero state ------------------------------------------------------
__global__ __launch_bounds__(256) void prep(float* v, float* r, float* Ap,
                                            float* sc) {
    const int i = blockIdx.x * 256 + threadIdx.x;
    v[i] = 0.f; r[i] = 0.f; Ap[i] = 0.f;
    if (i < 32) sc[i] = 0.f;
}

// --- p = r (copy), rs0 = r.r ----------------------------------------------
__global__ __launch_bounds__(256) void init_p_rs(const float* __restrict__ r,
                                                 float* __restrict__ p,
                                                 float* sc) {
    const int i = blockIdx.x * 256 + threadIdx.x;
    const float rv = r[i];
    p[i] = rv;
    wred_atomic(rv * rv, &sc[0]);   // RS
}

// --- tt = t.t (single block); also rotate rs <- rs_new, rs_new <- 0 -------
__global__ __launch_bounds__(1024) void dot_tt(const float* __restrict__ t,
                                               float* sc, int rotate) {
    const float4* t4 = (const float4*)t;
    const int i = threadIdx.x;
    float4 a = t4[i * 2], b = t4[i * 2 + 1];
    float acc = a.x*a.x + a.y*a.y + a.z*a.z + a.w*a.w
              + b.x*b.x + b.y*b.y + b.z*b.z + b.w*b.w;
    acc = wave_red(acc);
    __shared__ float wsum[16];
    if ((threadIdx.x & 63) == 0) wsum[threadIdx.x >> 6] = acc;
    __syncthreads();
    if (threadIdx.x == 0) {
        float tot = 0.f;
        #pragma unroll
        for (int w = 0; w < 16; ++w) tot += wsum[w];
        sc[1] = tot;                                 // TT = p.Ap (= ||Hp||^2)
        if (rotate) { sc[0] = sc[2]; sc[2] = 0.f; }  // RS <- RSN, RSN <- 0
    }
}

// --- v += a p; r -= a Ap; Ap = 0; rs_new += r.r ---------------------------
__global__ __launch_bounds__(256) void update_vr(float* __restrict__ v,
                                                 float* __restrict__ r,
                                                 const float* __restrict__ p,
                                                 float* __restrict__ Ap,
                                                 float* sc) {
    const int i = blockIdx.x * 256 + threadIdx.x;
    const float alpha = sc[0] / (sc[1] + EPSF);
    v[i] += alpha * p[i];
    const float rn = r[i] - alpha * Ap[i];
    r[i] = rn;
    Ap[i] = 0.f;            // pre-zero for next iteration's colmv atomics
    wred_atomic(rn * rn, &sc[2]);   // RSN
}

// --- p = r + beta p -------------------------------------------------------
__global__ __launch_bounds__(256) void p_update(const float* __restrict__ r,
                                                float* __restrict__ p,
                                                const float* __restrict__ sc) {
    const int i = blockIdx.x * 256 + threadIdx.x;
    const float beta = sc[2] / (sc[0] + EPSF);
    p[i] = r[i] + beta * p[i];
}

// --- time-domain metrics + difference signals + v output ------------------
// sc: 3 res2 | 4 |dq| | 5 dq2 | 6 qt2 | 7 |dv| | 8 dv2 | 9 vt2
//     10 sum_dq 11 alt_dq 12 sum_qt 13 alt_qt 14 sum_dv 15 alt_dv
//     16 sum_vt 17 alt_vt | 18 magsum_dv 19 magsum_dq
__global__ __launch_bounds__(256) void metrics1(const float* __restrict__ qh,
                                                const float* __restrict__ v,
                                                const float* __restrict__ x,
                                                const float* __restrict__ vt,
                                                const float* __restrict__ qt,
                                                float* __restrict__ dv,
                                                float* __restrict__ dq,
                                                float* sc,
                                                float* __restrict__ out) {
    const int i = blockIdx.x * 256 + threadIdx.x;
    const float qhv = qh[i], vv = v[i];
    const float xv = x[i], vtv = vt[i], qtv = qt[i];
    const float dqi = qhv - qtv, dvi = vv - vtv;
    dq[i] = dqi; dv[i] = dvi;
    out[i] = vv;
    const float sg = (i & 1) ? -1.f : 1.f;
    const float rx = qhv - xv;
    wred_atomic(rx * rx,    &sc[3]);
    wred_atomic(fabsf(dqi), &sc[4]);
    wred_atomic(dqi * dqi,  &sc[5]);
    wred_atomic(qtv * qtv,  &sc[6]);
    wred_atomic(fabsf(dvi), &sc[7]);
    wred_atomic(dvi * dvi,  &sc[8]);
    wred_atomic(vtv * vtv,  &sc[9]);
    wred_atomic(dqi,        &sc[10]);
    wred_atomic(sg * dqi,   &sc[11]);
    wred_atomic(qtv,        &sc[12]);
    wred_atomic(sg * qtv,   &sc[13]);
    wred_atomic(dvi,        &sc[14]);
    wred_atomic(sg * dvi,   &sc[15]);
    wred_atomic(vtv,        &sc[16]);
    wred_atomic(sg * vtv,   &sc[17]);
}

// --- direct rDFT magnitudes: one wave per bin k (0..4096) ------------------
__global__ __launch_bounds__(256) void dftmag(const float* __restrict__ dv,
                                              const float* __restrict__ dq,
                                              float* sc) {
    const int wave = threadIdx.x >> 6;
    const int lane = threadIdx.x & 63;
    const int k = blockIdx.x * 4 + wave;
    const float* sig = blockIdx.y ? dq : dv;
    float re = 0.f, im = 0.f;
    if (k <= 4096) {
        const float C = 2.0f * 3.14159265358979323846f / 8192.0f;
        int phase = (k * lane) & 8191;
        const int step = (k << 6) & 8191;
        for (int j = 0; j < 128; ++j) {
            const float s = sig[j * 64 + lane];   // coalesced across lanes
            float sn, cs;
            sincosf(C * (float)phase, &sn, &cs);
            re += s * cs; im += s * sn;           // sign of im irrelevant for |X|
            phase = (phase + step) & 8191;
        }
    }
    re = wave_red(re); im = wave_red(im);
    __shared__ float mg[4];
    if (lane == 0) mg[wave] = (k <= 4096) ? sqrtf(re * re + im * im) : 0.f;
    __syncthreads();
    if (threadIdx.x == 0)
        atomicAdd(&sc[18 + blockIdx.y], mg[0] + mg[1] + mg[2] + mg[3]);
}

// --- finalize 11 scalar outputs -------------------------------------------
__global__ void finalize(const float* __restrict__ sc,
                         float* __restrict__ out) {
    if (threadIdx.x == 0 && blockIdx.x == 0) {
        const float Nf = 8192.0f;
        // Parseval over rfft bins: sum|X_k|^2 = (N*sum(x^2)+X0^2+X_{N/2}^2)/2
        const float Sdq = 0.5f * (Nf * sc[5] + sc[10]*sc[10] + sc[11]*sc[11]);
        const float Sqt = 0.5f * (Nf * sc[6] + sc[12]*sc[12] + sc[13]*sc[13]);
        const float Sdv = 0.5f * (Nf * sc[8] + sc[14]*sc[14] + sc[15]*sc[15]);
        const float Svt = 0.5f * (Nf * sc[9] + sc[16]*sc[16] + sc[17]*sc[17]);
        out[8192 + 0]  = sqrtf(sc[3]);            // residual
        out[8192 + 1]  = sc[4] / Nf;              // mae_target
        out[8192 + 2]  = sc[5] / (sc[6] + EPSF);  // ce_target
        out[8192 + 3]  = sc[7] / Nf;              // mae
        out[8192 + 4]  = sc[8] / (sc[9] + EPSF);  // ce
        out[8192 + 5]  = sc[5] / Nf;              // mse_v_t_target
        out[8192 + 6]  = sc[8] / Nf;              // mse_v_t
        out[8192 + 7]  = sc[19] / 4097.0f;        // mae_target_f
        out[8192 + 8]  = Sdq / (Sqt + EPSF);      // ce_target_f
        out[8192 + 9]  = sc[18] / 4097.0f;        // mae_f
        out[8192 + 10] = Sdv / (Svt + EPSF);      // ce_f
    }
}

// ---------------------------------------------------------------------------
extern "C" void kernel_launch(void* const* d_in, const int* in_sizes, int n_in,
                              void* d_out, int out_size, void* d_ws, size_t ws_size,
                              hipStream_t stream) {
    // inputs: 0 n_iter (int,=32) | 1 x f32[N] | 2 H f32[N*N] | 3 v_truth | 4 q_truth | 5 L
    const float* x  = (const float*)d_in[1];
    const float* H  = (const float*)d_in[2];
    const float* vt = (const float*)d_in[3];
    const float* qt = (const float*)d_in[4];
    float* ws = (float*)d_ws;
    float* v  = ws;
    float* r  = ws + 8192;
    float* p  = ws + 16384;
    float* t  = ws + 24576;
    float* Ap = ws + 32768;
    float* qh = ws + 40960;
    float* dv = ws + 49152;
    float* dq = ws + 57344;
    float* sc = ws + 65536;
    float* out = (float*)d_out;

    prep<<<32, 256, 0, stream>>>(v, r, Ap, sc);
    colmv<<<512, 256, 0, stream>>>(H, x, r);         // r = b = H^T x
    init_p_rs<<<32, 256, 0, stream>>>(r, p, sc);     // p = r, rs = r.r

    for (int it = 0; it < NITER; ++it) {
        rowdot<<<2048, 256, 0, stream>>>(H, p, t);   // t = H p
        colmv<<<512, 256, 0, stream>>>(H, t, Ap);    // Ap = H^T t
        dot_tt<<<1, 1024, 0, stream>>>(t, sc, it > 0 ? 1 : 0); // tt (+rs rotate)
        update_vr<<<32, 256, 0, stream>>>(v, r, p, Ap, sc);
        p_update<<<32, 256, 0, stream>>>(r, p, sc);
    }

    rowdot<<<2048, 256, 0, stream>>>(H, v, qh);      // q_hat = H v
    metrics1<<<32, 256, 0, stream>>>(qh, v, x, vt, qt, dv, dq, sc, out);
    dim3 g(1025, 2);
    dftmag<<<g, 256, 0, stream>>>(dv, dq, sc);
    finalize<<<1, 64, 0, stream>>>(sc, out);
}

// Round 3
// 3623.516 us; speedup vs baseline: 1.0629x; 1.0629x over previous
//
#include <hip/hip_runtime.h>
#include <math.h>

// ---------------------------------------------------------------------------
// CGNR solver (fp32): v = argmin ||H v - x|| via CG on (H^T H) v = H^T x,
// 32 iters, then reconstruction + time/frequency metrics.
// N = 8192, H fp32 row-major. Memory-bound: 66 passes over 256 MB of H
// at ~6.7 TB/s -> ~2.64 ms floor. This round: 2 fused kernels per iteration.
//
// Scalar slots in sc[]: RS[it]=sc[it] (it=0..32), TT[it]=sc[40+it],
// metrics msc=sc+80 (indices 3..19), junk TT sink sc[120].
// ---------------------------------------------------------------------------

#define NN 8192
#define NITER 32
#define EPSF 1e-20f

__device__ __forceinline__ float wave_red(float v) {
    #pragma unroll
    for (int off = 32; off; off >>= 1) v += __shfl_xor(v, off, 64);
    return v;
}

__device__ __forceinline__ void wred_atomic(float v, float* addr) {
    v = wave_red(v);
    if ((threadIdx.x & 63) == 0) atomicAdd(addr, v);
}

// --- fused row pass: pn = r + beta*p ; t = H pn ; TT += ||t||^2 ; p_out=pn --
// one wave per row; 2048 blocks x 256 threads.
__global__ __launch_bounds__(256) void rowdot_f(const float* __restrict__ H,
                                                const float* __restrict__ r,
                                                const float* __restrict__ p,
                                                const float* __restrict__ sc,
                                                int bnum, int bden, int first,
                                                float* __restrict__ t,
                                                float* __restrict__ ttout,
                                                float* __restrict__ pout) {
    const int wave = threadIdx.x >> 6;
    const int lane = threadIdx.x & 63;
    const int row  = blockIdx.x * 4 + wave;
    const float beta = first ? 0.f : sc[bnum] / (sc[bden] + EPSF);
    const float4* Hrow = (const float4*)(H + (size_t)row * NN);
    const float4* r4   = (const float4*)r;
    const float4* p4   = (const float4*)p;
    float acc = 0.f;
    #pragma unroll 8
    for (int it = 0; it < 32; ++it) {
        const int idx = it * 64 + lane;
        float4 h  = Hrow[idx];
        float4 rv = r4[idx];
        float4 pv = p4[idx];
        const float px = rv.x + beta * pv.x;
        const float py = rv.y + beta * pv.y;
        const float pz = rv.z + beta * pv.z;
        const float pw = rv.w + beta * pv.w;
        acc += h.x * px + h.y * py + h.z * pz + h.w * pw;
    }
    acc = wave_red(acc);
    __shared__ float ws4[4];
    if (lane == 0) { t[row] = acc; ws4[wave] = acc * acc; }
    __syncthreads();
    if (threadIdx.x == 0)
        atomicAdd(ttout, ws4[0] + ws4[1] + ws4[2] + ws4[3]);
    if (pout != nullptr && blockIdx.x < 32) {
        const int gid = blockIdx.x * 256 + threadIdx.x;
        pout[gid] = r[gid] + beta * p[gid];
    }
}

// --- fused col pass: s = (H^T src)[col] in-block; then
//     mode 0: r=s, RS += s^2   (b = H^T x init)
//     mode 1: alpha=RS/TT; v += alpha p; r -= alpha s; RSout += r^2
// 256 blocks x 256 threads; block owns 32 line-aligned columns.
__global__ __launch_bounds__(256) void colmv_f(const float* __restrict__ H,
                                               const float* __restrict__ src,
                                               float* __restrict__ r,
                                               const float* __restrict__ p,
                                               float* __restrict__ v,
                                               const float* __restrict__ sc,
                                               int anum, int aden,
                                               float* __restrict__ rsout,
                                               int mode) {
    const int q  = threadIdx.x & 7;    // column quad within the 32-col group
    const int g  = threadIdx.x >> 3;   // row group 0..31
    const int c0 = blockIdx.x * 32 + q * 4;
    float a0 = 0.f, a1 = 0.f, a2 = 0.f, a3 = 0.f;
    #pragma unroll 16
    for (int step = 0; step < 256; ++step) {
        const int row = step * 32 + g;
        float4 u = *(const float4*)(H + (size_t)row * NN + c0);
        const float sv = src[row];
        a0 += u.x * sv; a1 += u.y * sv; a2 += u.z * sv; a3 += u.w * sv;
    }
    __shared__ float lds[32][33];
    lds[g][q * 4 + 0] = a0; lds[g][q * 4 + 1] = a1;
    lds[g][q * 4 + 2] = a2; lds[g][q * 4 + 3] = a3;
    __syncthreads();
    float rn2 = 0.f;
    if (threadIdx.x < 32) {
        float s = 0.f;
        #pragma unroll
        for (int gg = 0; gg < 32; ++gg) s += lds[gg][threadIdx.x];
        const int col = blockIdx.x * 32 + threadIdx.x;
        if (mode == 0) {
            r[col] = s;
            rn2 = s * s;
        } else {
            const float alpha = sc[anum] / (sc[aden] + EPSF);
            v[col] += alpha * p[col];
            const float rn = r[col] - alpha * s;
            r[col] = rn;
            rn2 = rn * rn;
        }
    }
    if (threadIdx.x < 64) {          // whole wave 0 active (uniform branch)
        rn2 = wave_red(rn2);
        if (threadIdx.x == 0) atomicAdd(rsout, rn2);
    }
}

// --- prep: zero v and scalar slots ----------------------------------------
__global__ __launch_bounds__(256) void prep(float* v, float* sc) {
    const int i = blockIdx.x * 256 + threadIdx.x;
    v[i] = 0.f;
    if (i < 128) sc[i] = 0.f;
}

// --- time-domain metrics + difference signals + v output ------------------
// msc: 3 res2 | 4 |dq| | 5 dq2 | 6 qt2 | 7 |dv| | 8 dv2 | 9 vt2
//      10 sum_dq 11 alt_dq 12 sum_qt 13 alt_qt 14 sum_dv 15 alt_dv
//      16 sum_vt 17 alt_vt | 18 magsum_dv 19 magsum_dq
__global__ __launch_bounds__(256) void metrics1(const float* __restrict__ qh,
                                                const float* __restrict__ v,
                                                const float* __restrict__ x,
                                                const float* __restrict__ vt,
                                                const float* __restrict__ qt,
                                                float* __restrict__ dv,
                                                float* __restrict__ dq,
                                                float* msc,
                                                float* __restrict__ out) {
    const int i = blockIdx.x * 256 + threadIdx.x;
    const float qhv = qh[i], vv = v[i];
    const float xv = x[i], vtv = vt[i], qtv = qt[i];
    const float dqi = qhv - qtv, dvi = vv - vtv;
    dq[i] = dqi; dv[i] = dvi;
    out[i] = vv;
    const float sg = (i & 1) ? -1.f : 1.f;
    const float rx = qhv - xv;
    wred_atomic(rx * rx,    &msc[3]);
    wred_atomic(fabsf(dqi), &msc[4]);
    wred_atomic(dqi * dqi,  &msc[5]);
    wred_atomic(qtv * qtv,  &msc[6]);
    wred_atomic(fabsf(dvi), &msc[7]);
    wred_atomic(dvi * dvi,  &msc[8]);
    wred_atomic(vtv * vtv,  &msc[9]);
    wred_atomic(dqi,        &msc[10]);
    wred_atomic(sg * dqi,   &msc[11]);
    wred_atomic(qtv,        &msc[12]);
    wred_atomic(sg * qtv,   &msc[13]);
    wred_atomic(dvi,        &msc[14]);
    wred_atomic(sg * dvi,   &msc[15]);
    wred_atomic(vtv,        &msc[16]);
    wred_atomic(sg * vtv,   &msc[17]);
}

// --- direct rDFT magnitudes: one wave per bin k (0..4096) ------------------
__global__ __launch_bounds__(256) void dftmag(const float* __restrict__ dv,
                                              const float* __restrict__ dq,
                                              float* msc) {
    const int wave = threadIdx.x >> 6;
    const int lane = threadIdx.x & 63;
    const int k = blockIdx.x * 4 + wave;
    const float* sig = blockIdx.y ? dq : dv;
    float re = 0.f, im = 0.f;
    if (k <= 4096) {
        const float C = 2.0f * 3.14159265358979323846f / 8192.0f;
        int phase = (k * lane) & 8191;
        const int step = (k << 6) & 8191;
        for (int j = 0; j < 128; ++j) {
            const float s = sig[j * 64 + lane];   // coalesced across lanes
            float sn, cs;
            sincosf(C * (float)phase, &sn, &cs);
            re += s * cs; im += s * sn;           // sign of im irrelevant for |X|
            phase = (phase + step) & 8191;
        }
    }
    re = wave_red(re); im = wave_red(im);
    __shared__ float mg[4];
    if (lane == 0) mg[wave] = (k <= 4096) ? sqrtf(re * re + im * im) : 0.f;
    __syncthreads();
    if (threadIdx.x == 0)
        atomicAdd(&msc[18 + blockIdx.y], mg[0] + mg[1] + mg[2] + mg[3]);
}

// --- finalize 11 scalar outputs -------------------------------------------
__global__ void finalize(const float* __restrict__ msc,
                         float* __restrict__ out) {
    if (threadIdx.x == 0 && blockIdx.x == 0) {
        const float Nf = 8192.0f;
        // Parseval over rfft bins: sum|X_k|^2 = (N*sum(x^2)+X0^2+X_{N/2}^2)/2
        const float Sdq = 0.5f * (Nf * msc[5] + msc[10]*msc[10] + msc[11]*msc[11]);
        const float Sqt = 0.5f * (Nf * msc[6] + msc[12]*msc[12] + msc[13]*msc[13]);
        const float Sdv = 0.5f * (Nf * msc[8] + msc[14]*msc[14] + msc[15]*msc[15]);
        const float Svt = 0.5f * (Nf * msc[9] + msc[16]*msc[16] + msc[17]*msc[17]);
        out[8192 + 0]  = sqrtf(msc[3]);             // residual
        out[8192 + 1]  = msc[4] / Nf;               // mae_target
        out[8192 + 2]  = msc[5] / (msc[6] + EPSF);  // ce_target
        out[8192 + 3]  = msc[7] / Nf;               // mae
        out[8192 + 4]  = msc[8] / (msc[9] + EPSF);  // ce
        out[8192 + 5]  = msc[5] / Nf;               // mse_v_t_target
        out[8192 + 6]  = msc[8] / Nf;               // mse_v_t
        out[8192 + 7]  = msc[19] / 4097.0f;         // mae_target_f
        out[8192 + 8]  = Sdq / (Sqt + EPSF);        // ce_target_f
        out[8192 + 9]  = msc[18] / 4097.0f;         // mae_f
        out[8192 + 10] = Sdv / (Svt + EPSF);        // ce_f
    }
}

// ---------------------------------------------------------------------------
extern "C" void kernel_launch(void* const* d_in, const int* in_sizes, int n_in,
                              void* d_out, int out_size, void* d_ws, size_t ws_size,
                              hipStream_t stream) {
    // inputs: 0 n_iter(=32) | 1 x f32[N] | 2 H f32[N*N] | 3 v_truth | 4 q_truth | 5 L
    const float* x  = (const float*)d_in[1];
    const float* H  = (const float*)d_in[2];
    const float* vt = (const float*)d_in[3];
    const float* qt = (const float*)d_in[4];
    float* ws = (float*)d_ws;
    float* v   = ws;
    float* r   = ws + 8192;
    float* pA  = ws + 16384;
    float* pB  = ws + 24576;
    float* t   = ws + 32768;
    float* qh  = ws + 40960;
    float* dv  = ws + 49152;
    float* dq  = ws + 57344;
    float* sc  = ws + 65536;   // RS[0..32]=sc[0..32], TT[it]=sc[40+it], junk sc[120]
    float* msc = sc + 80;
    float* out = (float*)d_out;

    prep<<<32, 256, 0, stream>>>(v, sc);
    // r = b = H^T x ; RS[0] = b.b
    colmv_f<<<256, 256, 0, stream>>>(H, x, r, nullptr, v, sc, 0, 0, &sc[0], 0);

    float* pbuf[2] = { pA, pB };
    for (int it = 0; it < NITER; ++it) {
        const float* pread = (it == 0) ? r : pbuf[(it - 1) & 1]; // beta=0 at it=0
        float* pwrite = pbuf[it & 1];
        // pn = r + beta p ; t = H pn ; TT[it] = t.t ; p <- pn
        rowdot_f<<<2048, 256, 0, stream>>>(H, r, pread, sc,
                                           it, it - 1, (it == 0) ? 1 : 0,
                                           t, &sc[40 + it], pwrite);
        // s = H^T t ; alpha = RS[it]/TT[it] ; v += alpha p ; r -= alpha s ;
        // RS[it+1] = r.r
        colmv_f<<<256, 256, 0, stream>>>(H, t, r, pwrite, v, sc,
                                         it, 40 + it, &sc[it + 1], 1);
    }

    // q_hat = H v  (beta=0 path, no p write)
    rowdot_f<<<2048, 256, 0, stream>>>(H, v, v, sc, 0, 0, 1,
                                       qh, &sc[120], nullptr);
    metrics1<<<32, 256, 0, stream>>>(qh, v, x, vt, qt, dv, dq, msc, out);
    dim3 g(1025, 2);
    dftmag<<<g, 256, 0, stream>>>(dv, dq, msc);
    finalize<<<1, 64, 0, stream>>>(sc + 80, out);
}

// Round 4
// 3479.301 us; speedup vs baseline: 1.1070x; 1.0414x over previous
//
#include <hip/hip_runtime.h>
#include <math.h>

// ---------------------------------------------------------------------------
// CGNR solver (fp32): v = argmin ||H v - x|| via CG on (H^T H) v = H^T x,
// 32 iters, then reconstruction + time/frequency metrics.
// N = 8192, H fp32 row-major. 65 passes over 268 MB of H.
// Round 4: 4 rows/wave in rowdot (4x less vector re-read), 16-wave/CU colmv
// with LDS-staged src, q_hat accumulated as sum(alpha_i t_i) -> no final pass.
//
// sc[] slots: RS[it]=sc[it] (0..32), TT[it]=sc[40+it], metrics msc=sc+80.
// ---------------------------------------------------------------------------

#define NN 8192
#define NITER 32
#define EPSF 1e-20f

__device__ __forceinline__ float wave_red(float v) {
    #pragma unroll
    for (int off = 32; off; off >>= 1) v += __shfl_xor(v, off, 64);
    return v;
}

__device__ __forceinline__ void wred_atomic(float v, float* addr) {
    v = wave_red(v);
    if ((threadIdx.x & 63) == 0) atomicAdd(addr, v);
}

// --- fused row pass: pn = r + beta*p ; t = H pn ; TT += ||t||^2 ; p_out=pn --
// 512 blocks x 256 threads; each wave owns 4 consecutive rows.
__global__ __launch_bounds__(256) void rowdot_f(const float* __restrict__ H,
                                                const float* __restrict__ r,
                                                const float* __restrict__ p,
                                                const float* __restrict__ sc,
                                                int bnum, int bden, int first,
                                                float* __restrict__ t,
                                                float* __restrict__ ttout,
                                                float* __restrict__ pout) {
    const int wave = threadIdx.x >> 6;
    const int lane = threadIdx.x & 63;
    const int r0   = (blockIdx.x * 4 + wave) * 4;   // first of 4 rows
    const float beta = first ? 0.f : sc[bnum] / (sc[bden] + EPSF);
    const float4* h0 = (const float4*)(H + (size_t)(r0 + 0) * NN);
    const float4* h1 = (const float4*)(H + (size_t)(r0 + 1) * NN);
    const float4* h2 = (const float4*)(H + (size_t)(r0 + 2) * NN);
    const float4* h3 = (const float4*)(H + (size_t)(r0 + 3) * NN);
    const float4* r4 = (const float4*)r;
    const float4* p4 = (const float4*)p;
    float a0 = 0.f, a1 = 0.f, a2 = 0.f, a3 = 0.f;
    #pragma unroll 4
    for (int it = 0; it < 32; ++it) {
        const int idx = it * 64 + lane;
        float4 rv = r4[idx];
        float4 pv = p4[idx];
        float4 u0 = h0[idx];
        float4 u1 = h1[idx];
        float4 u2 = h2[idx];
        float4 u3 = h3[idx];
        const float px = rv.x + beta * pv.x;
        const float py = rv.y + beta * pv.y;
        const float pz = rv.z + beta * pv.z;
        const float pw = rv.w + beta * pv.w;
        a0 += u0.x * px + u0.y * py + u0.z * pz + u0.w * pw;
        a1 += u1.x * px + u1.y * py + u1.z * pz + u1.w * pw;
        a2 += u2.x * px + u2.y * py + u2.z * pz + u2.w * pw;
        a3 += u3.x * px + u3.y * py + u3.z * pz + u3.w * pw;
    }
    a0 = wave_red(a0); a1 = wave_red(a1);
    a2 = wave_red(a2); a3 = wave_red(a3);
    __shared__ float ws4[4];
    if (lane == 0) {
        t[r0 + 0] = a0; t[r0 + 1] = a1; t[r0 + 2] = a2; t[r0 + 3] = a3;
        ws4[wave] = a0 * a0 + a1 * a1 + a2 * a2 + a3 * a3;
    }
    __syncthreads();
    if (threadIdx.x == 0)
        atomicAdd(ttout, ws4[0] + ws4[1] + ws4[2] + ws4[3]);
    if (pout != nullptr && blockIdx.x < 32) {
        const int gid = blockIdx.x * 256 + threadIdx.x;
        pout[gid] = r[gid] + beta * p[gid];
    }
}

// --- fused col pass: s = (H^T src)[col] in-block (src LDS-staged); then
//     mode 0: r=s, RS += s^2            (b = H^T x init)
//     mode 1: alpha=RS/TT; v += alpha p; qh += alpha src; r -= alpha s;
//             RSout += r^2
// 256 blocks x 1024 threads (16 waves/CU); block owns 32 line-aligned cols.
__global__ __launch_bounds__(1024) void colmv_f(const float* __restrict__ H,
                                                const float* __restrict__ src,
                                                float* __restrict__ r,
                                                const float* __restrict__ p,
                                                float* __restrict__ v,
                                                float* __restrict__ qh,
                                                const float* __restrict__ sc,
                                                int anum, int aden,
                                                float* __restrict__ rsout,
                                                int mode) {
    __shared__ float s[NN];            // staged src (32 KB)
    __shared__ float red[128][33];
    __shared__ float red2[8][33];
    {   // coalesced stage: 1024 threads x 8 floats
        const float4* s4 = (const float4*)src;
        float4* l4 = (float4*)s;
        l4[threadIdx.x * 2]     = s4[threadIdx.x * 2];
        l4[threadIdx.x * 2 + 1] = s4[threadIdx.x * 2 + 1];
    }
    __syncthreads();
    const int q  = threadIdx.x & 7;    // column quad (0..7) -> 32 cols
    const int g  = threadIdx.x >> 3;   // row group 0..127
    const int c0 = blockIdx.x * 32 + q * 4;
    float a0 = 0.f, a1 = 0.f, a2 = 0.f, a3 = 0.f;
    #pragma unroll 8
    for (int step = 0; step < 64; ++step) {
        const int row = step * 128 + g;
        float4 u = *(const float4*)(H + (size_t)row * NN + c0);
        const float sv = s[row];
        a0 += u.x * sv; a1 += u.y * sv; a2 += u.z * sv; a3 += u.w * sv;
    }
    red[g][q * 4 + 0] = a0; red[g][q * 4 + 1] = a1;
    red[g][q * 4 + 2] = a2; red[g][q * 4 + 3] = a3;
    __syncthreads();
    if (threadIdx.x < 256) {           // stage-1 reduce: 16 rows each
        const int col = threadIdx.x & 31, part = threadIdx.x >> 5;
        float ssum = 0.f;
        #pragma unroll
        for (int k = 0; k < 16; ++k) ssum += red[part * 16 + k][col];
        red2[part][col] = ssum;
    }
    __syncthreads();
    float rn2 = 0.f;
    if (threadIdx.x < 32) {            // stage-2 reduce + epilogue
        float ssum = 0.f;
        #pragma unroll
        for (int k = 0; k < 8; ++k) ssum += red2[k][threadIdx.x];
        const int col = blockIdx.x * 32 + threadIdx.x;
        if (mode == 0) {
            r[col] = ssum;
            rn2 = ssum * ssum;
        } else {
            const float alpha = sc[anum] / (sc[aden] + EPSF);
            v[col]  += alpha * p[col];
            qh[col] += alpha * s[col];          // q_hat = sum(alpha_i t_i)
            const float rn = r[col] - alpha * ssum;
            r[col] = rn;
            rn2 = rn * rn;
        }
    }
    if (threadIdx.x < 64) {            // wave 0 uniform: reduce + atomic
        rn2 = wave_red(rn2);
        if (threadIdx.x == 0) atomicAdd(rsout, rn2);
    }
}

// --- prep: zero v, qh and scalar slots ------------------------------------
__global__ __launch_bounds__(256) void prep(float* v, float* qh, float* sc) {
    const int i = blockIdx.x * 256 + threadIdx.x;
    v[i] = 0.f; qh[i] = 0.f;
    if (i < 128) sc[i] = 0.f;
}

// --- time-domain metrics + difference signals + v output ------------------
// msc: 3 res2 | 4 |dq| | 5 dq2 | 6 qt2 | 7 |dv| | 8 dv2 | 9 vt2
//      10 sum_dq 11 alt_dq 12 sum_qt 13 alt_qt 14 sum_dv 15 alt_dv
//      16 sum_vt 17 alt_vt | 18 magsum_dv 19 magsum_dq
__global__ __launch_bounds__(256) void metrics1(const float* __restrict__ qh,
                                                const float* __restrict__ v,
                                                const float* __restrict__ x,
                                                const float* __restrict__ vt,
                                                const float* __restrict__ qt,
                                                float* __restrict__ dv,
                                                float* __restrict__ dq,
                                                float* msc,
                                                float* __restrict__ out) {
    const int i = blockIdx.x * 256 + threadIdx.x;
    const float qhv = qh[i], vv = v[i];
    const float xv = x[i], vtv = vt[i], qtv = qt[i];
    const float dqi = qhv - qtv, dvi = vv - vtv;
    dq[i] = dqi; dv[i] = dvi;
    out[i] = vv;
    const float sg = (i & 1) ? -1.f : 1.f;
    const float rx = qhv - xv;
    wred_atomic(rx * rx,    &msc[3]);
    wred_atomic(fabsf(dqi), &msc[4]);
    wred_atomic(dqi * dqi,  &msc[5]);
    wred_atomic(qtv * qtv,  &msc[6]);
    wred_atomic(fabsf(dvi), &msc[7]);
    wred_atomic(dvi * dvi,  &msc[8]);
    wred_atomic(vtv * vtv,  &msc[9]);
    wred_atomic(dqi,        &msc[10]);
    wred_atomic(sg * dqi,   &msc[11]);
    wred_atomic(qtv,        &msc[12]);
    wred_atomic(sg * qtv,   &msc[13]);
    wred_atomic(dvi,        &msc[14]);
    wred_atomic(sg * dvi,   &msc[15]);
    wred_atomic(vtv,        &msc[16]);
    wred_atomic(sg * vtv,   &msc[17]);
}

// --- direct rDFT magnitudes: one wave per bin k (0..4096) ------------------
__global__ __launch_bounds__(256) void dftmag(const float* __restrict__ dv,
                                              const float* __restrict__ dq,
                                              float* msc) {
    const int wave = threadIdx.x >> 6;
    const int lane = threadIdx.x & 63;
    const int k = blockIdx.x * 4 + wave;
    const float* sig = blockIdx.y ? dq : dv;
    float re = 0.f, im = 0.f;
    if (k <= 4096) {
        const float C = 2.0f * 3.14159265358979323846f / 8192.0f;
        int phase = (k * lane) & 8191;
        const int step = (k << 6) & 8191;
        for (int j = 0; j < 128; ++j) {
            const float s = sig[j * 64 + lane];   // coalesced across lanes
            float sn, cs;
            sincosf(C * (float)phase, &sn, &cs);
            re += s * cs; im += s * sn;           // sign of im irrelevant for |X|
            phase = (phase + step) & 8191;
        }
    }
    re = wave_red(re); im = wave_red(im);
    __shared__ float mg[4];
    if (lane == 0) mg[wave] = (k <= 4096) ? sqrtf(re * re + im * im) : 0.f;
    __syncthreads();
    if (threadIdx.x == 0)
        atomicAdd(&msc[18 + blockIdx.y], mg[0] + mg[1] + mg[2] + mg[3]);
}

// --- finalize 11 scalar outputs -------------------------------------------
__global__ void finalize(const float* __restrict__ msc,
                         float* __restrict__ out) {
    if (threadIdx.x == 0 && blockIdx.x == 0) {
        const float Nf = 8192.0f;
        // Parseval over rfft bins: sum|X_k|^2 = (N*sum(x^2)+X0^2+X_{N/2}^2)/2
        const float Sdq = 0.5f * (Nf * msc[5] + msc[10]*msc[10] + msc[11]*msc[11]);
        const float Sqt = 0.5f * (Nf * msc[6] + msc[12]*msc[12] + msc[13]*msc[13]);
        const float Sdv = 0.5f * (Nf * msc[8] + msc[14]*msc[14] + msc[15]*msc[15]);
        const float Svt = 0.5f * (Nf * msc[9] + msc[16]*msc[16] + msc[17]*msc[17]);
        out[8192 + 0]  = sqrtf(msc[3]);             // residual
        out[8192 + 1]  = msc[4] / Nf;               // mae_target
        out[8192 + 2]  = msc[5] / (msc[6] + EPSF);  // ce_target
        out[8192 + 3]  = msc[7] / Nf;               // mae
        out[8192 + 4]  = msc[8] / (msc[9] + EPSF);  // ce
        out[8192 + 5]  = msc[5] / Nf;               // mse_v_t_target
        out[8192 + 6]  = msc[8] / Nf;               // mse_v_t
        out[8192 + 7]  = msc[19] / 4097.0f;         // mae_target_f
        out[8192 + 8]  = Sdq / (Sqt + EPSF);        // ce_target_f
        out[8192 + 9]  = msc[18] / 4097.0f;         // mae_f
        out[8192 + 10] = Sdv / (Svt + EPSF);        // ce_f
    }
}

// ---------------------------------------------------------------------------
extern "C" void kernel_launch(void* const* d_in, const int* in_sizes, int n_in,
                              void* d_out, int out_size, void* d_ws, size_t ws_size,
                              hipStream_t stream) {
    // inputs: 0 n_iter(=32) | 1 x f32[N] | 2 H f32[N*N] | 3 v_truth | 4 q_truth | 5 L
    const float* x  = (const float*)d_in[1];
    const float* H  = (const float*)d_in[2];
    const float* vt = (const float*)d_in[3];
    const float* qt = (const float*)d_in[4];
    float* ws = (float*)d_ws;
    float* v   = ws;
    float* r   = ws + 8192;
    float* pA  = ws + 16384;
    float* pB  = ws + 24576;
    float* t   = ws + 32768;
    float* qh  = ws + 40960;
    float* dv  = ws + 49152;
    float* dq  = ws + 57344;
    float* sc  = ws + 65536;   // RS[0..32], TT[it]=sc[40+it], msc=sc+80
    float* msc = sc + 80;
    float* out = (float*)d_out;

    prep<<<32, 256, 0, stream>>>(v, qh, sc);
    // r = b = H^T x ; RS[0] = b.b
    colmv_f<<<256, 1024, 0, stream>>>(H, x, r, nullptr, v, qh, sc,
                                      0, 0, &sc[0], 0);

    float* pbuf[2] = { pA, pB };
    for (int it = 0; it < NITER; ++it) {
        const float* pread = (it == 0) ? r : pbuf[(it - 1) & 1]; // beta=0 at it=0
        float* pwrite = pbuf[it & 1];
        // pn = r + beta p ; t = H pn ; TT[it] = t.t ; p <- pn
        rowdot_f<<<512, 256, 0, stream>>>(H, r, pread, sc,
                                          it, it - 1, (it == 0) ? 1 : 0,
                                          t, &sc[40 + it], pwrite);
        // s = H^T t ; alpha = RS[it]/TT[it] ; v += alpha p ; qh += alpha t ;
        // r -= alpha s ; RS[it+1] = r.r
        colmv_f<<<256, 1024, 0, stream>>>(H, t, r, pwrite, v, qh, sc,
                                          it, 40 + it, &sc[it + 1], 1);
    }

    metrics1<<<32, 256, 0, stream>>>(qh, v, x, vt, qt, dv, dq, msc, out);
    dim3 g(1025, 2);
    dftmag<<<g, 256, 0, stream>>>(dv, dq, msc);
    finalize<<<1, 64, 0, stream>>>(sc + 80, out);
}

// Round 5
// 2788.787 us; speedup vs baseline: 1.3811x; 1.2476x over previous
//
#include <hip/hip_runtime.h>
#include <hip/hip_fp16.h>
#include <math.h>

// ---------------------------------------------------------------------------
// CGNR solver: v = argmin ||H v - x|| via CG on (H^T H) v = H^T x, 32 iters,
// then reconstruction + time/frequency metrics.
// N = 8192. Round 5: H converted once to fp16 (134 MB, fits in 256 MiB L3);
// every pass reads half the bytes vs fp32. All accumulation fp32.
// Measured ceiling: ~5.4 TB/s combined read path regardless of schedule
// (rounds 2-4 all ~50 us/pass) -> bytes are the only lever.
//
// sc[] slots: RS[it]=sc[it] (0..32), TT[it]=sc[40+it], metrics msc=sc+80.
// ---------------------------------------------------------------------------

#define NN 8192
#define NITER 32
#define EPSF 1e-20f

typedef unsigned short ushort_t;

__device__ __forceinline__ float wave_red(float v) {
    #pragma unroll
    for (int off = 32; off; off >>= 1) v += __shfl_xor(v, off, 64);
    return v;
}

__device__ __forceinline__ void wred_atomic(float v, float* addr) {
    v = wave_red(v);
    if ((threadIdx.x & 63) == 0) atomicAdd(addr, v);
}

__device__ __forceinline__ void unpack8(uint4 u, float* f) {
    union { unsigned int i; __half2 h; } c0, c1, c2, c3;
    c0.i = u.x; c1.i = u.y; c2.i = u.z; c3.i = u.w;
    float2 f0 = __half22float2(c0.h);
    float2 f1 = __half22float2(c1.h);
    float2 f2 = __half22float2(c2.h);
    float2 f3 = __half22float2(c3.h);
    f[0] = f0.x; f[1] = f0.y; f[2] = f1.x; f[3] = f1.y;
    f[4] = f2.x; f[5] = f2.y; f[6] = f3.x; f[7] = f3.y;
}

// --- one-time H fp32 -> fp16 convert: thread handles 8 elems ---------------
__global__ __launch_bounds__(256) void h_convert(const float4* __restrict__ Hf,
                                                 uint4* __restrict__ Hh) {
    const size_t i = (size_t)blockIdx.x * 256 + threadIdx.x;
    float4 a = Hf[2 * i], b = Hf[2 * i + 1];
    __half2 h0 = __floats2half2_rn(a.x, a.y);
    __half2 h1 = __floats2half2_rn(a.z, a.w);
    __half2 h2 = __floats2half2_rn(b.x, b.y);
    __half2 h3 = __floats2half2_rn(b.z, b.w);
    uint4 o;
    o.x = *(unsigned int*)&h0; o.y = *(unsigned int*)&h1;
    o.z = *(unsigned int*)&h2; o.w = *(unsigned int*)&h3;
    Hh[i] = o;
}

// --- fused row pass: pn = r + beta*p ; t = H pn ; TT += ||t||^2 ; p_out=pn --
// 512 blocks x 256 threads; each wave owns 4 consecutive rows.
template <int HM>
__global__ __launch_bounds__(256) void rowdot_f(const void* __restrict__ Hp,
                                                const float* __restrict__ r,
                                                const float* __restrict__ p,
                                                const float* __restrict__ sc,
                                                int bnum, int bden, int first,
                                                float* __restrict__ t,
                                                float* __restrict__ ttout,
                                                float* __restrict__ pout) {
    const int wave = threadIdx.x >> 6;
    const int lane = threadIdx.x & 63;
    const int r0   = (blockIdx.x * 4 + wave) * 4;
    const float beta = first ? 0.f : sc[bnum] / (sc[bden] + EPSF);
    const float4* r4 = (const float4*)r;
    const float4* p4 = (const float4*)p;
    float a0 = 0.f, a1 = 0.f, a2 = 0.f, a3 = 0.f;
    if (HM) {
        const uint4* h0 = (const uint4*)((const ushort_t*)Hp + (size_t)(r0 + 0) * NN);
        const uint4* h1 = (const uint4*)((const ushort_t*)Hp + (size_t)(r0 + 1) * NN);
        const uint4* h2 = (const uint4*)((const ushort_t*)Hp + (size_t)(r0 + 2) * NN);
        const uint4* h3 = (const uint4*)((const ushort_t*)Hp + (size_t)(r0 + 3) * NN);
        #pragma unroll 2
        for (int it = 0; it < 16; ++it) {
            const int idx = it * 64 + lane;      // uint4 index (8 halves)
            float4 ra = r4[2 * idx], rb = r4[2 * idx + 1];
            float4 pa = p4[2 * idx], pb = p4[2 * idx + 1];
            float pn[8];
            pn[0] = ra.x + beta * pa.x; pn[1] = ra.y + beta * pa.y;
            pn[2] = ra.z + beta * pa.z; pn[3] = ra.w + beta * pa.w;
            pn[4] = rb.x + beta * pb.x; pn[5] = rb.y + beta * pb.y;
            pn[6] = rb.z + beta * pb.z; pn[7] = rb.w + beta * pb.w;
            uint4 u0 = h0[idx], u1 = h1[idx], u2 = h2[idx], u3 = h3[idx];
            float f[8];
            unpack8(u0, f);
            a0 += f[0]*pn[0] + f[1]*pn[1] + f[2]*pn[2] + f[3]*pn[3]
                + f[4]*pn[4] + f[5]*pn[5] + f[6]*pn[6] + f[7]*pn[7];
            unpack8(u1, f);
            a1 += f[0]*pn[0] + f[1]*pn[1] + f[2]*pn[2] + f[3]*pn[3]
                + f[4]*pn[4] + f[5]*pn[5] + f[6]*pn[6] + f[7]*pn[7];
            unpack8(u2, f);
            a2 += f[0]*pn[0] + f[1]*pn[1] + f[2]*pn[2] + f[3]*pn[3]
                + f[4]*pn[4] + f[5]*pn[5] + f[6]*pn[6] + f[7]*pn[7];
            unpack8(u3, f);
            a3 += f[0]*pn[0] + f[1]*pn[1] + f[2]*pn[2] + f[3]*pn[3]
                + f[4]*pn[4] + f[5]*pn[5] + f[6]*pn[6] + f[7]*pn[7];
        }
    } else {
        const float* H = (const float*)Hp;
        const float4* h0 = (const float4*)(H + (size_t)(r0 + 0) * NN);
        const float4* h1 = (const float4*)(H + (size_t)(r0 + 1) * NN);
        const float4* h2 = (const float4*)(H + (size_t)(r0 + 2) * NN);
        const float4* h3 = (const float4*)(H + (size_t)(r0 + 3) * NN);
        #pragma unroll 4
        for (int it = 0; it < 32; ++it) {
            const int idx = it * 64 + lane;
            float4 rv = r4[idx];
            float4 pv = p4[idx];
            float4 u0 = h0[idx], u1 = h1[idx], u2 = h2[idx], u3 = h3[idx];
            const float px = rv.x + beta * pv.x;
            const float py = rv.y + beta * pv.y;
            const float pz = rv.z + beta * pv.z;
            const float pw = rv.w + beta * pv.w;
            a0 += u0.x * px + u0.y * py + u0.z * pz + u0.w * pw;
            a1 += u1.x * px + u1.y * py + u1.z * pz + u1.w * pw;
            a2 += u2.x * px + u2.y * py + u2.z * pz + u2.w * pw;
            a3 += u3.x * px + u3.y * py + u3.z * pz + u3.w * pw;
        }
    }
    a0 = wave_red(a0); a1 = wave_red(a1);
    a2 = wave_red(a2); a3 = wave_red(a3);
    __shared__ float ws4[4];
    if (lane == 0) {
        t[r0 + 0] = a0; t[r0 + 1] = a1; t[r0 + 2] = a2; t[r0 + 3] = a3;
        ws4[wave] = a0 * a0 + a1 * a1 + a2 * a2 + a3 * a3;
    }
    __syncthreads();
    if (threadIdx.x == 0)
        atomicAdd(ttout, ws4[0] + ws4[1] + ws4[2] + ws4[3]);
    if (pout != nullptr && blockIdx.x < 32) {
        const int gid = blockIdx.x * 256 + threadIdx.x;
        pout[gid] = r[gid] + beta * p[gid];
    }
}

// --- fused col pass: ssum = (H^T src)[col] in-block (src LDS-staged); then
//     mode 0: r=ssum, RS += ssum^2       (b = H^T x init)
//     mode 1: alpha=RS/TT; v += alpha p; qh += alpha src; r -= alpha ssum;
//             RSout += r^2
// 256 blocks x 1024 threads; block owns 32 line-aligned cols.
template <int HM>
__global__ __launch_bounds__(1024) void colmv_f(const void* __restrict__ Hp,
                                                const float* __restrict__ src,
                                                float* __restrict__ r,
                                                const float* __restrict__ p,
                                                float* __restrict__ v,
                                                float* __restrict__ qh,
                                                const float* __restrict__ sc,
                                                int anum, int aden,
                                                float* __restrict__ rsout,
                                                int mode) {
    __shared__ float s[NN];            // staged src (32 KB)
    __shared__ float red_w[16][33];    // one partial per wave per col
    {   // coalesced stage: 1024 threads x 8 floats
        const float4* s4 = (const float4*)src;
        float4* l4 = (float4*)s;
        l4[threadIdx.x * 2]     = s4[threadIdx.x * 2];
        l4[threadIdx.x * 2 + 1] = s4[threadIdx.x * 2 + 1];
    }
    __syncthreads();
    const int wave = threadIdx.x >> 6;
    const int lane = threadIdx.x & 63;
    if (HM) {
        const int q = threadIdx.x & 3;     // 4 octets of 8 cols
        const int g = threadIdx.x >> 2;    // row group 0..255
        const int c0 = blockIdx.x * 32 + q * 8;
        const ushort_t* Hh = (const ushort_t*)Hp;
        float acc[8] = {0.f, 0.f, 0.f, 0.f, 0.f, 0.f, 0.f, 0.f};
        #pragma unroll 4
        for (int step = 0; step < 32; ++step) {
            const int row = step * 256 + g;
            uint4 u = *(const uint4*)(Hh + (size_t)row * NN + c0);
            const float sv = s[row];
            float f[8];
            unpack8(u, f);
            #pragma unroll
            for (int k = 0; k < 8; ++k) acc[k] += f[k] * sv;
        }
        // in-wave reduce over the 16 lanes sharing q (stride 4)
        #pragma unroll
        for (int k = 0; k < 8; ++k) {
            #pragma unroll
            for (int off = 4; off < 64; off <<= 1)
                acc[k] += __shfl_xor(acc[k], off, 64);
        }
        if (lane < 4) {
            #pragma unroll
            for (int k = 0; k < 8; ++k) red_w[wave][lane * 8 + k] = acc[k];
        }
    } else {
        const int q = threadIdx.x & 7;     // 8 quads of 4 cols
        const int g = threadIdx.x >> 3;    // row group 0..127
        const int c0 = blockIdx.x * 32 + q * 4;
        const float* H = (const float*)Hp;
        float acc[4] = {0.f, 0.f, 0.f, 0.f};
        #pragma unroll 8
        for (int step = 0; step < 64; ++step) {
            const int row = step * 128 + g;
            float4 u = *(const float4*)(H + (size_t)row * NN + c0);
            const float sv = s[row];
            acc[0] += u.x * sv; acc[1] += u.y * sv;
            acc[2] += u.z * sv; acc[3] += u.w * sv;
        }
        #pragma unroll
        for (int k = 0; k < 4; ++k) {
            #pragma unroll
            for (int off = 8; off < 64; off <<= 1)
                acc[k] += __shfl_xor(acc[k], off, 64);
        }
        if (lane < 8) {
            #pragma unroll
            for (int k = 0; k < 4; ++k) red_w[wave][lane * 4 + k] = acc[k];
        }
    }
    __syncthreads();
    float rn2 = 0.f;
    if (threadIdx.x < 32) {
        float ssum = 0.f;
        #pragma unroll
        for (int w = 0; w < 16; ++w) ssum += red_w[w][threadIdx.x];
        const int col = blockIdx.x * 32 + threadIdx.x;
        if (mode == 0) {
            r[col] = ssum;
            rn2 = ssum * ssum;
        } else {
            const float alpha = sc[anum] / (sc[aden] + EPSF);
            v[col]  += alpha * p[col];
            qh[col] += alpha * s[col];          // q_hat = sum(alpha_i t_i)
            const float rn = r[col] - alpha * ssum;
            r[col] = rn;
            rn2 = rn * rn;
        }
    }
    if (threadIdx.x < 64) {
        rn2 = wave_red(rn2);
        if (threadIdx.x == 0) atomicAdd(rsout, rn2);
    }
}

// --- prep: zero v, qh and scalar slots ------------------------------------
__global__ __launch_bounds__(256) void prep(float* v, float* qh, float* sc) {
    const int i = blockIdx.x * 256 + threadIdx.x;
    v[i] = 0.f; qh[i] = 0.f;
    if (i < 128) sc[i] = 0.f;
}

// --- time-domain metrics + difference signals + v output ------------------
__global__ __launch_bounds__(256) void metrics1(const float* __restrict__ qh,
                                                const float* __restrict__ v,
                                                const float* __restrict__ x,
                                                const float* __restrict__ vt,
                                                const float* __restrict__ qt,
                                                float* __restrict__ dv,
                                                float* __restrict__ dq,
                                                float* msc,
                                                float* __restrict__ out) {
    const int i = blockIdx.x * 256 + threadIdx.x;
    const float qhv = qh[i], vv = v[i];
    const float xv = x[i], vtv = vt[i], qtv = qt[i];
    const float dqi = qhv - qtv, dvi = vv - vtv;
    dq[i] = dqi; dv[i] = dvi;
    out[i] = vv;
    const float sg = (i & 1) ? -1.f : 1.f;
    const float rx = qhv - xv;
    wred_atomic(rx * rx,    &msc[3]);
    wred_atomic(fabsf(dqi), &msc[4]);
    wred_atomic(dqi * dqi,  &msc[5]);
    wred_atomic(qtv * qtv,  &msc[6]);
    wred_atomic(fabsf(dvi), &msc[7]);
    wred_atomic(dvi * dvi,  &msc[8]);
    wred_atomic(vtv * vtv,  &msc[9]);
    wred_atomic(dqi,        &msc[10]);
    wred_atomic(sg * dqi,   &msc[11]);
    wred_atomic(qtv,        &msc[12]);
    wred_atomic(sg * qtv,   &msc[13]);
    wred_atomic(dvi,        &msc[14]);
    wred_atomic(sg * dvi,   &msc[15]);
    wred_atomic(vtv,        &msc[16]);
    wred_atomic(sg * vtv,   &msc[17]);
}

// --- direct rDFT magnitudes: one wave per bin k (0..4096) ------------------
__global__ __launch_bounds__(256) void dftmag(const float* __restrict__ dv,
                                              const float* __restrict__ dq,
                                              float* msc) {
    const int wave = threadIdx.x >> 6;
    const int lane = threadIdx.x & 63;
    const int k = blockIdx.x * 4 + wave;
    const float* sig = blockIdx.y ? dq : dv;
    float re = 0.f, im = 0.f;
    if (k <= 4096) {
        const float C = 2.0f * 3.14159265358979323846f / 8192.0f;
        int phase = (k * lane) & 8191;
        const int step = (k << 6) & 8191;
        for (int j = 0; j < 128; ++j) {
            const float s = sig[j * 64 + lane];
            float sn, cs;
            sincosf(C * (float)phase, &sn, &cs);
            re += s * cs; im += s * sn;
            phase = (phase + step) & 8191;
        }
    }
    re = wave_red(re); im = wave_red(im);
    __shared__ float mg[4];
    if (lane == 0) mg[wave] = (k <= 4096) ? sqrtf(re * re + im * im) : 0.f;
    __syncthreads();
    if (threadIdx.x == 0)
        atomicAdd(&msc[18 + blockIdx.y], mg[0] + mg[1] + mg[2] + mg[3]);
}

// --- finalize 11 scalar outputs -------------------------------------------
__global__ void finalize(const float* __restrict__ msc,
                         float* __restrict__ out) {
    if (threadIdx.x == 0 && blockIdx.x == 0) {
        const float Nf = 8192.0f;
        const float Sdq = 0.5f * (Nf * msc[5] + msc[10]*msc[10] + msc[11]*msc[11]);
        const float Sqt = 0.5f * (Nf * msc[6] + msc[12]*msc[12] + msc[13]*msc[13]);
        const float Sdv = 0.5f * (Nf * msc[8] + msc[14]*msc[14] + msc[15]*msc[15]);
        const float Svt = 0.5f * (Nf * msc[9] + msc[16]*msc[16] + msc[17]*msc[17]);
        out[8192 + 0]  = sqrtf(msc[3]);
        out[8192 + 1]  = msc[4] / Nf;
        out[8192 + 2]  = msc[5] / (msc[6] + EPSF);
        out[8192 + 3]  = msc[7] / Nf;
        out[8192 + 4]  = msc[8] / (msc[9] + EPSF);
        out[8192 + 5]  = msc[5] / Nf;
        out[8192 + 6]  = msc[8] / Nf;
        out[8192 + 7]  = msc[19] / 4097.0f;
        out[8192 + 8]  = Sdq / (Sqt + EPSF);
        out[8192 + 9]  = msc[18] / 4097.0f;
        out[8192 + 10] = Sdv / (Svt + EPSF);
    }
}

// ---------------------------------------------------------------------------
extern "C" void kernel_launch(void* const* d_in, const int* in_sizes, int n_in,
                              void* d_out, int out_size, void* d_ws, size_t ws_size,
                              hipStream_t stream) {
    const float* x  = (const float*)d_in[1];
    const float* H  = (const float*)d_in[2];
    const float* vt = (const float*)d_in[3];
    const float* qt = (const float*)d_in[4];

    const size_t HH_BYTES = (size_t)NN * NN * 2;         // 134,217,728
    const size_t NEED = HH_BYTES + 80000ull * 4;
    const bool hm = (ws_size >= NEED);

    ushort_t* Hh = (ushort_t*)d_ws;
    float* vecs = hm ? (float*)((char*)d_ws + HH_BYTES) : (float*)d_ws;
    float* v   = vecs;
    float* r   = vecs + 8192;
    float* pA  = vecs + 16384;
    float* pB  = vecs + 24576;
    float* t   = vecs + 32768;
    float* qh  = vecs + 40960;
    float* dv  = vecs + 49152;
    float* dq  = vecs + 57344;
    float* sc  = vecs + 65536;
    float* msc = sc + 80;
    float* out = (float*)d_out;
    const void* Hp = hm ? (const void*)Hh : (const void*)H;

    if (hm)
        h_convert<<<32768, 256, 0, stream>>>((const float4*)H, (uint4*)Hh);
    prep<<<32, 256, 0, stream>>>(v, qh, sc);

    if (hm)
        colmv_f<1><<<256, 1024, 0, stream>>>(Hp, x, r, nullptr, v, qh, sc,
                                             0, 0, &sc[0], 0);
    else
        colmv_f<0><<<256, 1024, 0, stream>>>(Hp, x, r, nullptr, v, qh, sc,
                                             0, 0, &sc[0], 0);

    float* pbuf[2] = { pA, pB };
    for (int it = 0; it < NITER; ++it) {
        const float* pread = (it == 0) ? r : pbuf[(it - 1) & 1];
        float* pwrite = pbuf[it & 1];
        if (hm) {
            rowdot_f<1><<<512, 256, 0, stream>>>(Hp, r, pread, sc,
                                                 it, it - 1, (it == 0) ? 1 : 0,
                                                 t, &sc[40 + it], pwrite);
            colmv_f<1><<<256, 1024, 0, stream>>>(Hp, t, r, pwrite, v, qh, sc,
                                                 it, 40 + it, &sc[it + 1], 1);
        } else {
            rowdot_f<0><<<512, 256, 0, stream>>>(Hp, r, pread, sc,
                                                 it, it - 1, (it == 0) ? 1 : 0,
                                                 t, &sc[40 + it], pwrite);
            colmv_f<0><<<256, 1024, 0, stream>>>(Hp, t, r, pwrite, v, qh, sc,
                                                 it, 40 + it, &sc[it + 1], 1);
        }
    }

    metrics1<<<32, 256, 0, stream>>>(qh, v, x, vt, qt, dv, dq, msc, out);
    dim3 g(1025, 2);
    dftmag<<<g, 256, 0, stream>>>(dv, dq, msc);
    finalize<<<1, 64, 0, stream>>>(sc + 80, out);
}

// Round 6
// 2353.034 us; speedup vs baseline: 1.6369x; 1.1852x over previous
//
#include <hip/hip_runtime.h>
#include <hip/hip_fp16.h>
#include <math.h>

// ---------------------------------------------------------------------------
// CGNR solver: v = argmin ||H v - x|| via CG on (H^T H) v = H^T x, 32 iters,
// then reconstruction + time/frequency metrics.  N = 8192.
// Round 6: H stored once as fp16 Hh AND fp16 transposed Hht (268 MB in ws).
// Both CG passes are then fully-coalesced row-streams (no strided col reads,
// no atomic s-vector), 1024 blocks x 256 thr = 4 waves/SIMD each.
// Fallbacks: ws too small for transpose -> round-5 fp16 colmv; ws too small
// for fp16 at all -> fp32 direct.
//
// sc[] slots: RS[it]=sc[it] (0..32), TT[it]=sc[40+it], metrics msc=sc+80.
// ---------------------------------------------------------------------------

#define NN 8192
#define NITER 32
#define EPSF 1e-20f

typedef unsigned short ushort_t;

__device__ __forceinline__ float wave_red(float v) {
    #pragma unroll
    for (int off = 32; off; off >>= 1) v += __shfl_xor(v, off, 64);
    return v;
}

__device__ __forceinline__ void wred_atomic(float v, float* addr) {
    v = wave_red(v);
    if ((threadIdx.x & 63) == 0) atomicAdd(addr, v);
}

__device__ __forceinline__ void unpack8(uint4 u, float* f) {
    union { unsigned int i; __half2 h; } c0, c1, c2, c3;
    c0.i = u.x; c1.i = u.y; c2.i = u.z; c3.i = u.w;
    float2 f0 = __half22float2(c0.h);
    float2 f1 = __half22float2(c1.h);
    float2 f2 = __half22float2(c2.h);
    float2 f3 = __half22float2(c3.h);
    f[0] = f0.x; f[1] = f0.y; f[2] = f1.x; f[3] = f1.y;
    f[4] = f2.x; f[5] = f2.y; f[6] = f3.x; f[7] = f3.y;
}

__device__ __forceinline__ float dot8(uint4 u, const float* w) {
    float f[8];
    unpack8(u, f);
    return f[0]*w[0] + f[1]*w[1] + f[2]*w[2] + f[3]*w[3]
         + f[4]*w[4] + f[5]*w[5] + f[6]*w[6] + f[7]*w[7];
}

// --- one-time: H fp32 -> fp16 normal + fp16 transposed (64x64 tiles) -------
__global__ __launch_bounds__(256) void h_convert_t(const float* __restrict__ Hf,
                                                   ushort_t* __restrict__ Hh,
                                                   ushort_t* __restrict__ Hht) {
    __shared__ ushort_t tile[64][72];   // stride 144 B (16B-aligned rows)
    const int r0 = blockIdx.x * 64, c0 = blockIdx.y * 64;
    const int row = threadIdx.x >> 2;          // 0..63
    const int cc  = (threadIdx.x & 3) * 16;    // 0,16,32,48
    const float4* src = (const float4*)(Hf + (size_t)(r0 + row) * NN + c0 + cc);
    ushort_t hv[16];
    #pragma unroll
    for (int k = 0; k < 4; ++k) {
        float4 f = src[k];
        hv[4*k+0] = __half_as_ushort(__float2half_rn(f.x));
        hv[4*k+1] = __half_as_ushort(__float2half_rn(f.y));
        hv[4*k+2] = __half_as_ushort(__float2half_rn(f.z));
        hv[4*k+3] = __half_as_ushort(__float2half_rn(f.w));
    }
    ushort_t* dstn = Hh + (size_t)(r0 + row) * NN + c0 + cc;
    ((uint4*)dstn)[0] = ((const uint4*)hv)[0];
    ((uint4*)dstn)[1] = ((const uint4*)hv)[1];
    ((uint4*)&tile[row][cc])[0] = ((const uint4*)hv)[0];
    ((uint4*)&tile[row][cc])[1] = ((const uint4*)hv)[1];
    __syncthreads();
    // transposed write: out-row oc (orig col), out-col chunk occ (orig rows)
    const int oc  = threadIdx.x >> 2;
    const int occ = (threadIdx.x & 3) * 16;
    ushort_t tv[16];
    #pragma unroll
    for (int k = 0; k < 16; ++k) tv[k] = tile[occ + k][oc];
    ushort_t* dstt = Hht + (size_t)(c0 + oc) * NN + r0 + occ;
    ((uint4*)dstt)[0] = ((const uint4*)tv)[0];
    ((uint4*)dstt)[1] = ((const uint4*)tv)[1];
}

// --- one-time: H fp32 -> fp16 (no transpose; hm1 fallback) -----------------
__global__ __launch_bounds__(256) void h_convert(const float4* __restrict__ Hf,
                                                 uint4* __restrict__ Hh) {
    const size_t i = (size_t)blockIdx.x * 256 + threadIdx.x;
    float4 a = Hf[2 * i], b = Hf[2 * i + 1];
    __half2 h0 = __floats2half2_rn(a.x, a.y);
    __half2 h1 = __floats2half2_rn(a.z, a.w);
    __half2 h2 = __floats2half2_rn(b.x, b.y);
    __half2 h3 = __floats2half2_rn(b.z, b.w);
    uint4 o;
    o.x = *(unsigned int*)&h0; o.y = *(unsigned int*)&h1;
    o.z = *(unsigned int*)&h2; o.w = *(unsigned int*)&h3;
    Hh[i] = o;
}

// --- pass A: pn = r + beta*p ; t = Hh pn ; TT += ||t||^2 ; p_out = pn -------
// 1024 blocks x 256 thr; wave owns 2 consecutive rows.
__global__ __launch_bounds__(256) void rowdot_t(const ushort_t* __restrict__ Hh,
                                                const float* __restrict__ r,
                                                const float* __restrict__ p,
                                                const float* __restrict__ sc,
                                                int bnum, int bden, int first,
                                                float* __restrict__ t,
                                                float* __restrict__ ttout,
                                                float* __restrict__ pout) {
    const int wave = threadIdx.x >> 6;
    const int lane = threadIdx.x & 63;
    const int r0   = (blockIdx.x * 4 + wave) * 2;
    const float beta = first ? 0.f : sc[bnum] / (sc[bden] + EPSF);
    const uint4* h0 = (const uint4*)(Hh + (size_t)(r0 + 0) * NN);
    const uint4* h1 = (const uint4*)(Hh + (size_t)(r0 + 1) * NN);
    const float4* r4 = (const float4*)r;
    const float4* p4 = (const float4*)p;
    float a0 = 0.f, a1 = 0.f;
    #pragma unroll 4
    for (int it = 0; it < 16; ++it) {
        const int idx = it * 64 + lane;          // uint4 index (8 halves)
        float4 ra = r4[2 * idx], rb = r4[2 * idx + 1];
        float4 pa = p4[2 * idx], pb = p4[2 * idx + 1];
        uint4 u0 = h0[idx], u1 = h1[idx];
        float pn[8];
        pn[0] = ra.x + beta * pa.x; pn[1] = ra.y + beta * pa.y;
        pn[2] = ra.z + beta * pa.z; pn[3] = ra.w + beta * pa.w;
        pn[4] = rb.x + beta * pb.x; pn[5] = rb.y + beta * pb.y;
        pn[6] = rb.z + beta * pb.z; pn[7] = rb.w + beta * pb.w;
        a0 += dot8(u0, pn);
        a1 += dot8(u1, pn);
    }
    a0 = wave_red(a0); a1 = wave_red(a1);
    __shared__ float ws4[4];
    if (lane == 0) {
        t[r0] = a0; t[r0 + 1] = a1;
        ws4[wave] = a0 * a0 + a1 * a1;
    }
    __syncthreads();
    if (threadIdx.x == 0)
        atomicAdd(ttout, ws4[0] + ws4[1] + ws4[2] + ws4[3]);
    if (pout != nullptr && blockIdx.x < 32) {
        const int gid = blockIdx.x * 256 + threadIdx.x;
        pout[gid] = r[gid] + beta * p[gid];
    }
}

// --- pass B: s = Hht-row . t  (== (H^T t)[col]) ; then
//     mode 0: r = s, RS += s^2                    (b = H^T x init)
//     mode 1: alpha=RS/TT; v += alpha p; qh += alpha t; r -= alpha s;
//             RSout += r^2
// 1024 blocks x 256 thr; wave owns 2 consecutive cols.
__global__ __launch_bounds__(256) void rowdot_a(const ushort_t* __restrict__ Hht,
                                                const float* __restrict__ tsrc,
                                                float* __restrict__ r,
                                                const float* __restrict__ p,
                                                float* __restrict__ v,
                                                float* __restrict__ qh,
                                                const float* __restrict__ sc,
                                                int anum, int aden,
                                                float* __restrict__ rsout,
                                                int mode) {
    const int wave = threadIdx.x >> 6;
    const int lane = threadIdx.x & 63;
    const int c0   = (blockIdx.x * 4 + wave) * 2;
    const uint4* h0 = (const uint4*)(Hht + (size_t)(c0 + 0) * NN);
    const uint4* h1 = (const uint4*)(Hht + (size_t)(c0 + 1) * NN);
    const float4* t4 = (const float4*)tsrc;
    float a0 = 0.f, a1 = 0.f;
    #pragma unroll 4
    for (int it = 0; it < 16; ++it) {
        const int idx = it * 64 + lane;
        float4 ta = t4[2 * idx], tb = t4[2 * idx + 1];
        uint4 u0 = h0[idx], u1 = h1[idx];
        float tw[8];
        tw[0] = ta.x; tw[1] = ta.y; tw[2] = ta.z; tw[3] = ta.w;
        tw[4] = tb.x; tw[5] = tb.y; tw[6] = tb.z; tw[7] = tb.w;
        a0 += dot8(u0, tw);
        a1 += dot8(u1, tw);
    }
    a0 = wave_red(a0); a1 = wave_red(a1);
    float rn2 = 0.f;
    if (lane == 0) {
        if (mode == 0) {
            r[c0] = a0; r[c0 + 1] = a1;
            rn2 = a0 * a0 + a1 * a1;
        } else {
            const float alpha = sc[anum] / (sc[aden] + EPSF);
            v[c0]      += alpha * p[c0];
            v[c0 + 1]  += alpha * p[c0 + 1];
            qh[c0]     += alpha * tsrc[c0];
            qh[c0 + 1] += alpha * tsrc[c0 + 1];
            const float rn0 = r[c0]     - alpha * a0;
            const float rn1 = r[c0 + 1] - alpha * a1;
            r[c0] = rn0; r[c0 + 1] = rn1;
            rn2 = rn0 * rn0 + rn1 * rn1;
        }
    }
    __shared__ float ws4[4];
    if (lane == 0) ws4[wave] = rn2;
    __syncthreads();
    if (threadIdx.x == 0)
        atomicAdd(rsout, ws4[0] + ws4[1] + ws4[2] + ws4[3]);
}

// ===================== round-5 fallback kernels (hm1 / fp32) ================
template <int HM>
__global__ __launch_bounds__(256) void rowdot_f(const void* __restrict__ Hp,
                                                const float* __restrict__ r,
                                                const float* __restrict__ p,
                                                const float* __restrict__ sc,
                                                int bnum, int bden, int first,
                                                float* __restrict__ t,
                                                float* __restrict__ ttout,
                                                float* __restrict__ pout) {
    const int wave = threadIdx.x >> 6;
    const int lane = threadIdx.x & 63;
    const int r0   = (blockIdx.x * 4 + wave) * 4;
    const float beta = first ? 0.f : sc[bnum] / (sc[bden] + EPSF);
    const float4* r4 = (const float4*)r;
    const float4* p4 = (const float4*)p;
    float a0 = 0.f, a1 = 0.f, a2 = 0.f, a3 = 0.f;
    if (HM) {
        const uint4* h0 = (const uint4*)((const ushort_t*)Hp + (size_t)(r0 + 0) * NN);
        const uint4* h1 = (const uint4*)((const ushort_t*)Hp + (size_t)(r0 + 1) * NN);
        const uint4* h2 = (const uint4*)((const ushort_t*)Hp + (size_t)(r0 + 2) * NN);
        const uint4* h3 = (const uint4*)((const ushort_t*)Hp + (size_t)(r0 + 3) * NN);
        #pragma unroll 2
        for (int it = 0; it < 16; ++it) {
            const int idx = it * 64 + lane;
            float4 ra = r4[2 * idx], rb = r4[2 * idx + 1];
            float4 pa = p4[2 * idx], pb = p4[2 * idx + 1];
            float pn[8];
            pn[0] = ra.x + beta * pa.x; pn[1] = ra.y + beta * pa.y;
            pn[2] = ra.z + beta * pa.z; pn[3] = ra.w + beta * pa.w;
            pn[4] = rb.x + beta * pb.x; pn[5] = rb.y + beta * pb.y;
            pn[6] = rb.z + beta * pb.z; pn[7] = rb.w + beta * pb.w;
            uint4 u0 = h0[idx], u1 = h1[idx], u2 = h2[idx], u3 = h3[idx];
            a0 += dot8(u0, pn); a1 += dot8(u1, pn);
            a2 += dot8(u2, pn); a3 += dot8(u3, pn);
        }
    } else {
        const float* H = (const float*)Hp;
        const float4* h0 = (const float4*)(H + (size_t)(r0 + 0) * NN);
        const float4* h1 = (const float4*)(H + (size_t)(r0 + 1) * NN);
        const float4* h2 = (const float4*)(H + (size_t)(r0 + 2) * NN);
        const float4* h3 = (const float4*)(H + (size_t)(r0 + 3) * NN);
        #pragma unroll 4
        for (int it = 0; it < 32; ++it) {
            const int idx = it * 64 + lane;
            float4 rv = r4[idx];
            float4 pv = p4[idx];
            float4 u0 = h0[idx], u1 = h1[idx], u2 = h2[idx], u3 = h3[idx];
            const float px = rv.x + beta * pv.x;
            const float py = rv.y + beta * pv.y;
            const float pz = rv.z + beta * pv.z;
            const float pw = rv.w + beta * pv.w;
            a0 += u0.x * px + u0.y * py + u0.z * pz + u0.w * pw;
            a1 += u1.x * px + u1.y * py + u1.z * pz + u1.w * pw;
            a2 += u2.x * px + u2.y * py + u2.z * pz + u2.w * pw;
            a3 += u3.x * px + u3.y * py + u3.z * pz + u3.w * pw;
        }
    }
    a0 = wave_red(a0); a1 = wave_red(a1);
    a2 = wave_red(a2); a3 = wave_red(a3);
    __shared__ float ws4[4];
    if (lane == 0) {
        t[r0 + 0] = a0; t[r0 + 1] = a1; t[r0 + 2] = a2; t[r0 + 3] = a3;
        ws4[wave] = a0 * a0 + a1 * a1 + a2 * a2 + a3 * a3;
    }
    __syncthreads();
    if (threadIdx.x == 0)
        atomicAdd(ttout, ws4[0] + ws4[1] + ws4[2] + ws4[3]);
    if (pout != nullptr && blockIdx.x < 32) {
        const int gid = blockIdx.x * 256 + threadIdx.x;
        pout[gid] = r[gid] + beta * p[gid];
    }
}

template <int HM>
__global__ __launch_bounds__(1024) void colmv_f(const void* __restrict__ Hp,
                                                const float* __restrict__ src,
                                                float* __restrict__ r,
                                                const float* __restrict__ p,
                                                float* __restrict__ v,
                                                float* __restrict__ qh,
                                                const float* __restrict__ sc,
                                                int anum, int aden,
                                                float* __restrict__ rsout,
                                                int mode) {
    __shared__ float s[NN];
    __shared__ float red_w[16][33];
    {
        const float4* s4 = (const float4*)src;
        float4* l4 = (float4*)s;
        l4[threadIdx.x * 2]     = s4[threadIdx.x * 2];
        l4[threadIdx.x * 2 + 1] = s4[threadIdx.x * 2 + 1];
    }
    __syncthreads();
    const int wave = threadIdx.x >> 6;
    const int lane = threadIdx.x & 63;
    if (HM) {
        const int q = threadIdx.x & 3;
        const int g = threadIdx.x >> 2;
        const int c0 = blockIdx.x * 32 + q * 8;
        const ushort_t* Hh = (const ushort_t*)Hp;
        float acc[8] = {0.f,0.f,0.f,0.f,0.f,0.f,0.f,0.f};
        #pragma unroll 4
        for (int step = 0; step < 32; ++step) {
            const int row = step * 256 + g;
            uint4 u = *(const uint4*)(Hh + (size_t)row * NN + c0);
            const float sv = s[row];
            float f[8];
            unpack8(u, f);
            #pragma unroll
            for (int k = 0; k < 8; ++k) acc[k] += f[k] * sv;
        }
        #pragma unroll
        for (int k = 0; k < 8; ++k) {
            #pragma unroll
            for (int off = 4; off < 64; off <<= 1)
                acc[k] += __shfl_xor(acc[k], off, 64);
        }
        if (lane < 4) {
            #pragma unroll
            for (int k = 0; k < 8; ++k) red_w[wave][lane * 8 + k] = acc[k];
        }
    } else {
        const int q = threadIdx.x & 7;
        const int g = threadIdx.x >> 3;
        const int c0 = blockIdx.x * 32 + q * 4;
        const float* H = (const float*)Hp;
        float acc[4] = {0.f,0.f,0.f,0.f};
        #pragma unroll 8
        for (int step = 0; step < 64; ++step) {
            const int row = step * 128 + g;
            float4 u = *(const float4*)(H + (size_t)row * NN + c0);
            const float sv = s[row];
            acc[0] += u.x * sv; acc[1] += u.y * sv;
            acc[2] += u.z * sv; acc[3] += u.w * sv;
        }
        #pragma unroll
        for (int k = 0; k < 4; ++k) {
            #pragma unroll
            for (int off = 8; off < 64; off <<= 1)
                acc[k] += __shfl_xor(acc[k], off, 64);
        }
        if (lane < 8) {
            #pragma unroll
            for (int k = 0; k < 4; ++k) red_w[wave][lane * 4 + k] = acc[k];
        }
    }
    __syncthreads();
    float rn2 = 0.f;
    if (threadIdx.x < 32) {
        float ssum = 0.f;
        #pragma unroll
        for (int w = 0; w < 16; ++w) ssum += red_w[w][threadIdx.x];
        const int col = blockIdx.x * 32 + threadIdx.x;
        if (mode == 0) {
            r[col] = ssum;
            rn2 = ssum * ssum;
        } else {
            const float alpha = sc[anum] / (sc[aden] + EPSF);
            v[col]  += alpha * p[col];
            qh[col] += alpha * s[col];
            const float rn = r[col] - alpha * ssum;
            r[col] = rn;
            rn2 = rn * rn;
        }
    }
    if (threadIdx.x < 64) {
        rn2 = wave_red(rn2);
        if (threadIdx.x == 0) atomicAdd(rsout, rn2);
    }
}

// --- prep: zero v, qh and scalar slots ------------------------------------
__global__ __launch_bounds__(256) void prep(float* v, float* qh, float* sc) {
    const int i = blockIdx.x * 256 + threadIdx.x;
    v[i] = 0.f; qh[i] = 0.f;
    if (i < 128) sc[i] = 0.f;
}

// --- time-domain metrics + difference signals + v output ------------------
__global__ __launch_bounds__(256) void metrics1(const float* __restrict__ qh,
                                                const float* __restrict__ v,
                                                const float* __restrict__ x,
                                                const float* __restrict__ vt,
                                                const float* __restrict__ qt,
                                                float* __restrict__ dv,
                                                float* __restrict__ dq,
                                                float* msc,
                                                float* __restrict__ out) {
    const int i = blockIdx.x * 256 + threadIdx.x;
    const float qhv = qh[i], vv = v[i];
    const float xv = x[i], vtv = vt[i], qtv = qt[i];
    const float dqi = qhv - qtv, dvi = vv - vtv;
    dq[i] = dqi; dv[i] = dvi;
    out[i] = vv;
    const float sg = (i & 1) ? -1.f : 1.f;
    const float rx = qhv - xv;
    wred_atomic(rx * rx,    &msc[3]);
    wred_atomic(fabsf(dqi), &msc[4]);
    wred_atomic(dqi * dqi,  &msc[5]);
    wred_atomic(qtv * qtv,  &msc[6]);
    wred_atomic(fabsf(dvi), &msc[7]);
    wred_atomic(dvi * dvi,  &msc[8]);
    wred_atomic(vtv * vtv,  &msc[9]);
    wred_atomic(dqi,        &msc[10]);
    wred_atomic(sg * dqi,   &msc[11]);
    wred_atomic(qtv,        &msc[12]);
    wred_atomic(sg * qtv,   &msc[13]);
    wred_atomic(dvi,        &msc[14]);
    wred_atomic(sg * dvi,   &msc[15]);
    wred_atomic(vtv,        &msc[16]);
    wred_atomic(sg * vtv,   &msc[17]);
}

// --- direct rDFT magnitudes: one wave per bin k (0..4096) ------------------
__global__ __launch_bounds__(256) void dftmag(const float* __restrict__ dv,
                                              const float* __restrict__ dq,
                                              float* msc) {
    const int wave = threadIdx.x >> 6;
    const int lane = threadIdx.x & 63;
    const int k = blockIdx.x * 4 + wave;
    const float* sig = blockIdx.y ? dq : dv;
    float re = 0.f, im = 0.f;
    if (k <= 4096) {
        const float C = 2.0f * 3.14159265358979323846f / 8192.0f;
        int phase = (k * lane) & 8191;
        const int step = (k << 6) & 8191;
        for (int j = 0; j < 128; ++j) {
            const float s = sig[j * 64 + lane];
            float sn, cs;
            sincosf(C * (float)phase, &sn, &cs);
            re += s * cs; im += s * sn;
            phase = (phase + step) & 8191;
        }
    }
    re = wave_red(re); im = wave_red(im);
    __shared__ float mg[4];
    if (lane == 0) mg[wave] = (k <= 4096) ? sqrtf(re * re + im * im) : 0.f;
    __syncthreads();
    if (threadIdx.x == 0)
        atomicAdd(&msc[18 + blockIdx.y], mg[0] + mg[1] + mg[2] + mg[3]);
}

// --- finalize 11 scalar outputs -------------------------------------------
__global__ void finalize(const float* __restrict__ msc,
                         float* __restrict__ out) {
    if (threadIdx.x == 0 && blockIdx.x == 0) {
        const float Nf = 8192.0f;
        const float Sdq = 0.5f * (Nf * msc[5] + msc[10]*msc[10] + msc[11]*msc[11]);
        const float Sqt = 0.5f * (Nf * msc[6] + msc[12]*msc[12] + msc[13]*msc[13]);
        const float Sdv = 0.5f * (Nf * msc[8] + msc[14]*msc[14] + msc[15]*msc[15]);
        const float Svt = 0.5f * (Nf * msc[9] + msc[16]*msc[16] + msc[17]*msc[17]);
        out[8192 + 0]  = sqrtf(msc[3]);
        out[8192 + 1]  = msc[4] / Nf;
        out[8192 + 2]  = msc[5] / (msc[6] + EPSF);
        out[8192 + 3]  = msc[7] / Nf;
        out[8192 + 4]  = msc[8] / (msc[9] + EPSF);
        out[8192 + 5]  = msc[5] / Nf;
        out[8192 + 6]  = msc[8] / Nf;
        out[8192 + 7]  = msc[19] / 4097.0f;
        out[8192 + 8]  = Sdq / (Sqt + EPSF);
        out[8192 + 9]  = msc[18] / 4097.0f;
        out[8192 + 10] = Sdv / (Svt + EPSF);
    }
}

// ---------------------------------------------------------------------------
extern "C" void kernel_launch(void* const* d_in, const int* in_sizes, int n_in,
                              void* d_out, int out_size, void* d_ws, size_t ws_size,
                              hipStream_t stream) {
    const float* x  = (const float*)d_in[1];
    const float* H  = (const float*)d_in[2];
    const float* vt = (const float*)d_in[3];
    const float* qt = (const float*)d_in[4];

    const size_t HH_BYTES = (size_t)NN * NN * 2;           // 134,217,728
    const size_t VEC_BYTES = 80000ull * 4;
    const int tier = (ws_size >= 2 * HH_BYTES + VEC_BYTES) ? 2
                   : (ws_size >= HH_BYTES + VEC_BYTES)     ? 1 : 0;

    ushort_t* Hh  = (ushort_t*)d_ws;
    ushort_t* Hht = (ushort_t*)((char*)d_ws + HH_BYTES);
    float* vecs = (tier == 2) ? (float*)((char*)d_ws + 2 * HH_BYTES)
                : (tier == 1) ? (float*)((char*)d_ws + HH_BYTES)
                              : (float*)d_ws;
    float* v   = vecs;
    float* r   = vecs + 8192;
    float* pA  = vecs + 16384;
    float* pB  = vecs + 24576;
    float* t   = vecs + 32768;
    float* qh  = vecs + 40960;
    float* dv  = vecs + 49152;
    float* dq  = vecs + 57344;
    float* sc  = vecs + 65536;
    float* msc = sc + 80;
    float* out = (float*)d_out;
    float* pbuf[2] = { pA, pB };

    if (tier == 2) {
        dim3 tg(128, 128);
        h_convert_t<<<tg, 256, 0, stream>>>(H, Hh, Hht);
        prep<<<32, 256, 0, stream>>>(v, qh, sc);
        // r = b = H^T x ; RS[0] = b.b
        rowdot_a<<<1024, 256, 0, stream>>>(Hht, x, r, nullptr, v, qh, sc,
                                           0, 0, &sc[0], 0);
        for (int it = 0; it < NITER; ++it) {
            const float* pread = (it == 0) ? r : pbuf[(it - 1) & 1];
            float* pwrite = pbuf[it & 1];
            rowdot_t<<<1024, 256, 0, stream>>>(Hh, r, pread, sc,
                                               it, it - 1, (it == 0) ? 1 : 0,
                                               t, &sc[40 + it], pwrite);
            rowdot_a<<<1024, 256, 0, stream>>>(Hht, t, r, pwrite, v, qh, sc,
                                               it, 40 + it, &sc[it + 1], 1);
        }
    } else if (tier == 1) {
        h_convert<<<32768, 256, 0, stream>>>((const float4*)H, (uint4*)Hh);
        prep<<<32, 256, 0, stream>>>(v, qh, sc);
        colmv_f<1><<<256, 1024, 0, stream>>>(Hh, x, r, nullptr, v, qh, sc,
                                             0, 0, &sc[0], 0);
        for (int it = 0; it < NITER; ++it) {
            const float* pread = (it == 0) ? r : pbuf[(it - 1) & 1];
            float* pwrite = pbuf[it & 1];
            rowdot_f<1><<<512, 256, 0, stream>>>(Hh, r, pread, sc,
                                                 it, it - 1, (it == 0) ? 1 : 0,
                                                 t, &sc[40 + it], pwrite);
            colmv_f<1><<<256, 1024, 0, stream>>>(Hh, t, r, pwrite, v, qh, sc,
                                                 it, 40 + it, &sc[it + 1], 1);
        }
    } else {
        prep<<<32, 256, 0, stream>>>(v, qh, sc);
        colmv_f<0><<<256, 1024, 0, stream>>>(H, x, r, nullptr, v, qh, sc,
                                             0, 0, &sc[0], 0);
        for (int it = 0; it < NITER; ++it) {
            const float* pread = (it == 0) ? r : pbuf[(it - 1) & 1];
            float* pwrite = pbuf[it & 1];
            rowdot_f<0><<<512, 256, 0, stream>>>(H, r, pread, sc,
                                                 it, it - 1, (it == 0) ? 1 : 0,
                                                 t, &sc[40 + it], pwrite);
            colmv_f<0><<<256, 1024, 0, stream>>>(H, t, r, pwrite, v, qh, sc,
                                                 it, 40 + it, &sc[it + 1], 1);
        }
    }

    metrics1<<<32, 256, 0, stream>>>(qh, v, x, vt, qt, dv, dq, msc, out);
    dim3 g(1025, 2);
    dftmag<<<g, 256, 0, stream>>>(dv, dq, msc);
    finalize<<<1, 64, 0, stream>>>(sc + 80, out);
}